// Round 1
// baseline (920.369 us; speedup 1.0000x reference)
//
#include <hip/hip_runtime.h>
#include <math.h>

constexpr int NN  = 50000;   // nodes
constexpr int EE  = 800000;  // edges
constexpr int INF_ = 256;    // input feat
constexpr int HF  = 128;     // hidden
constexpr int CC  = 50;      // classes
constexpr long NH = (long)NN * HF;
#define EPSV 1e-5f

enum { EPI_RELU = 0, EPI_NONE = 1, EPI_BN = 2, EPI_BN_RES = 3 };

// ---------------- graph preprocessing ----------------

__global__ void count_deg_kernel(const int* __restrict__ src, const int* __restrict__ dst,
                                 int* __restrict__ indeg, int* __restrict__ outdeg) {
  int e = blockIdx.x * 256 + threadIdx.x;
  if (e < EE) {
    atomicAdd(&indeg[dst[e]], 1);
    atomicAdd(&outdeg[src[e]], 1);
  }
}

__global__ void inv_kernel(const int* __restrict__ indeg, const int* __restrict__ outdeg,
                           float* __restrict__ inv_mean, float* __restrict__ inv_in,
                           float* __restrict__ inv_out) {
  int i = blockIdx.x * 256 + threadIdx.x;
  if (i < NN) {
    float di = fmaxf((float)indeg[i], 1.f);
    float dz = fmaxf((float)outdeg[i], 1.f);
    inv_mean[i] = 1.f / di;
    inv_in[i]  = rsqrtf(di);
    inv_out[i] = rsqrtf(dz);
  }
}

// exclusive scan of counts -> excl, per-block totals -> bsum (nullable)
__global__ __launch_bounds__(256) void scan_block_kernel(const int* __restrict__ counts,
                                                         int* excl, int* bsum, int n) {
  __shared__ int sh[256];
  int i = blockIdx.x * 256 + threadIdx.x;
  int v = (i < n) ? counts[i] : 0;
  sh[threadIdx.x] = v;
  __syncthreads();
  #pragma unroll
  for (int off = 1; off < 256; off <<= 1) {
    int tv = (threadIdx.x >= off) ? sh[threadIdx.x - off] : 0;
    __syncthreads();
    sh[threadIdx.x] += tv;
    __syncthreads();
  }
  if (i < n) excl[i] = sh[threadIdx.x] - v;
  if (threadIdx.x == 255 && bsum) bsum[blockIdx.x] = sh[255];
}

__global__ void add_offsets_kernel(int* __restrict__ row_ptr, const int* __restrict__ bsum,
                                   int* __restrict__ cursor) {
  int i = blockIdx.x * 256 + threadIdx.x;
  if (i < NN) {
    int v = row_ptr[i] + bsum[blockIdx.x];
    row_ptr[i] = v;
    cursor[i]  = v;
  }
  if (i == NN) row_ptr[NN] = EE;
}

__global__ void fill_csr_kernel(const int* __restrict__ src, const int* __restrict__ dst,
                                int* __restrict__ cursor, int* __restrict__ col) {
  int e = blockIdx.x * 256 + threadIdx.x;
  if (e < EE) {
    int p = atomicAdd(&cursor[dst[e]], 1);
    col[p] = src[e];
  }
}

// ---------------- SpMM: out[dst] = dscale[dst] * sum_{e: dst} x[src]*(sscale[src]?) ----------------

template<bool SRC_SCALE>
__global__ __launch_bounds__(128) void spmm_kernel(
    const int* __restrict__ row_ptr, const int* __restrict__ cols,
    const float* __restrict__ x, const float* __restrict__ sscale,
    const float* __restrict__ dscale, float* __restrict__ out) {
  int node = blockIdx.x;
  int f = threadIdx.x;
  int e = row_ptr[node], end = row_ptr[node + 1];
  float acc = 0.f;
  for (; e < end; ++e) {
    int s = cols[e];
    float v = x[(long)s * HF + f];
    if (SRC_SCALE) v *= sscale[s];
    acc += v;
  }
  out[(long)node * HF + f] = acc * dscale[node];
}

// ---------------- attention gate + gated residual (in-place safe over `a`) ----------------

__global__ __launch_bounds__(128) void attn_hatt_kernel(
    const float* a, const float* __restrict__ w2, const float* __restrict__ b2,
    const float* __restrict__ h0, const float* __restrict__ agg, float* hatt) {
  int r = blockIdx.x, f = threadIdx.x;
  long idx = (long)r * HF + f;
  float v = a[idx] * w2[f];
  #pragma unroll
  for (int off = 32; off >= 1; off >>= 1) v += __shfl_down(v, off, 64);
  __shared__ float red[2];
  if ((f & 63) == 0) red[f >> 6] = v;
  __syncthreads();
  float dot = red[0] + red[1] + b2[0];
  float s = 1.f / (1.f + __expf(-dot));
  hatt[idx] = h0[idx] + agg[idx] * s;
}

// ---------------- tiled fp32 GEMM: out = epi( [A1|A2] @ W + bias ) ----------------
// K = KT*16 (A2 supplies k>=128 when KT==16). Tile: 64 rows x NJ*16 cols, 256 threads.

template<int KT, int NJ, int EPI>
__global__ __launch_bounds__(256) void gemm_kernel(
    const float* __restrict__ A1, int lda1,
    const float* __restrict__ A2, int lda2,
    const float* __restrict__ W, int ldw,
    const float* __restrict__ bias,
    const float* __restrict__ g, const float* __restrict__ be,
    const float* __restrict__ mu, const float* __restrict__ va,
    const float* __restrict__ res,
    float* __restrict__ out, int ldc) {
  constexpr int NC = NJ * 16;
  __shared__ float As[16][68];   // transposed A tile, padded (+4) -> 2-way max on write
  __shared__ float Ws[16][NC];
  const int t = threadIdx.x;
  const int tx = t & 15, ty = t >> 4;
  const int brow = blockIdx.x * 64;

  float acc[4][NJ];
  #pragma unroll
  for (int i = 0; i < 4; ++i)
    #pragma unroll
    for (int j = 0; j < NJ; ++j) acc[i][j] = 0.f;

  for (int kt = 0; kt < KT; ++kt) {
    const bool second = (KT == 16) && (kt >= 8);
    const float* Ap = second ? A2 : A1;
    const int lda = second ? lda2 : lda1;
    const int kb = (second ? (kt - 8) : kt) * 16;
    #pragma unroll
    for (int it = 0; it < 4; ++it) {
      int idx = t + 256 * it;              // 0..1023
      int r = idx >> 4, kk = idx & 15;
      int grow = brow + r;
      float v = (grow < NN) ? Ap[(long)grow * lda + kb + kk] : 0.f;
      As[kk][r] = v;
    }
    const int kw = kt * 16;
    #pragma unroll
    for (int it = 0; it < (16 * NC) / 256; ++it) {
      int idx = t + 256 * it;
      int kk = idx / NC, c = idx % NC;
      float v = (c < ldw) ? W[(kw + kk) * ldw + c] : 0.f;
      Ws[kk][c] = v;
    }
    __syncthreads();
    #pragma unroll
    for (int kk = 0; kk < 16; ++kk) {
      float a0 = As[kk][ty * 4 + 0];
      float a1 = As[kk][ty * 4 + 1];
      float a2 = As[kk][ty * 4 + 2];
      float a3 = As[kk][ty * 4 + 3];
      #pragma unroll
      for (int j = 0; j < NJ; ++j) {
        float b = Ws[kk][tx + 16 * j];     // stride-16 cols: conflict-free
        acc[0][j] = fmaf(a0, b, acc[0][j]);
        acc[1][j] = fmaf(a1, b, acc[1][j]);
        acc[2][j] = fmaf(a2, b, acc[2][j]);
        acc[3][j] = fmaf(a3, b, acc[3][j]);
      }
    }
    __syncthreads();
  }

  #pragma unroll
  for (int j = 0; j < NJ; ++j) {
    int c = tx + 16 * j;
    if (c >= ldc) continue;
    float bb = bias ? bias[c] : 0.f;
    float scale = 1.f, shift = 0.f;
    if (EPI == EPI_BN || EPI == EPI_BN_RES) {
      scale = g[c] * rsqrtf(va[c] + EPSV);
      shift = be[c] - mu[c] * scale;
    }
    #pragma unroll
    for (int i = 0; i < 4; ++i) {
      int r = brow + ty * 4 + i;
      if (r >= NN) continue;
      float v = acc[i][j] + bb;
      if (EPI == EPI_RELU) {
        v = fmaxf(v, 0.f);
      } else if (EPI == EPI_BN || EPI == EPI_BN_RES) {
        v = fmaxf(v * scale + shift, 0.f);
        if (EPI == EPI_BN_RES) v += res[(long)r * HF + c];
      }
      out[(long)r * ldc + c] = v;
    }
  }
}

// ---------------- launch ----------------

extern "C" void kernel_launch(void* const* d_in, const int* in_sizes, int n_in,
                              void* d_out, int out_size, void* d_ws, size_t ws_size,
                              hipStream_t stream) {
  const float* features = (const float*)d_in[0];
  const int*   src      = (const int*)d_in[1];
  const int*   dst      = (const int*)d_in[2];
  const float* w_in     = (const float*)d_in[3];
  const float* b_in     = (const float*)d_in[4];
  const float* gc_w     = (const float*)d_in[5];
  const float* gc_b     = (const float*)d_in[6];
  const float* bn_gamma = (const float*)d_in[7];
  const float* bn_beta  = (const float*)d_in[8];
  const float* bn_mean  = (const float*)d_in[9];
  const float* bn_var   = (const float*)d_in[10];
  const float* attn_w1  = (const float*)d_in[11];
  const float* attn_b1  = (const float*)d_in[12];
  const float* attn_w2  = (const float*)d_in[13];
  const float* attn_b2  = (const float*)d_in[14];
  const float* agg_w    = (const float*)d_in[15];
  const float* agg_b    = (const float*)d_in[16];
  const float* out_w    = (const float*)d_in[17];
  const float* out_b    = (const float*)d_in[18];
  float* out = (float*)d_out;

  float* fbase   = (float*)d_ws;
  float* W0 = fbase;                 // h0 -> spmm scratch
  float* W1 = fbase + NH;            // neigh -> a -> h_att -> h(final)
  float* W2 = fbase + 2 * NH;        // agg -> h(L0) -> h(L2)
  float* inv_mean = fbase + 3 * NH;
  float* inv_in   = inv_mean + NN;
  float* inv_out  = inv_in + NN;
  int* indeg   = (int*)(inv_out + NN);
  int* outdeg  = indeg + NN;
  int* row_ptr = outdeg + NN;        // NN+1
  int* cursor  = row_ptr + NN + 1;
  int* bsum    = cursor + NN;        // 256
  int* col     = bsum + 256;         // EE

  dim3 b256(256), b128(128);
  const int gE = (EE + 255) / 256, gN = (NN + 255) / 256;
  const int gblocks = (NN + 63) / 64;

  hipMemsetAsync(indeg, 0, sizeof(int) * 2 * NN, stream);
  count_deg_kernel<<<gE, b256, 0, stream>>>(src, dst, indeg, outdeg);
  inv_kernel<<<gN, b256, 0, stream>>>(indeg, outdeg, inv_mean, inv_in, inv_out);
  scan_block_kernel<<<gN, b256, 0, stream>>>(indeg, row_ptr, bsum, NN);
  scan_block_kernel<<<1, b256, 0, stream>>>(bsum, bsum, nullptr, gN);
  add_offsets_kernel<<<gN, b256, 0, stream>>>(row_ptr, bsum, cursor);
  fill_csr_kernel<<<gE, b256, 0, stream>>>(src, dst, cursor, col);

  // h0 = relu(features @ w_in + b_in)            -> W0
  gemm_kernel<16, 8, EPI_RELU><<<gblocks, b256, 0, stream>>>(
      features, INF_, features + 128, INF_, w_in, HF, b_in,
      nullptr, nullptr, nullptr, nullptr, nullptr, W0, HF);
  // neigh = mean-agg(h0)                          -> W1
  spmm_kernel<false><<<NN, b128, 0, stream>>>(row_ptr, col, W0, nullptr, inv_mean, W1);
  // agg = relu([h0|neigh] @ agg_w + agg_b)        -> W2
  gemm_kernel<16, 8, EPI_RELU><<<gblocks, b256, 0, stream>>>(
      W0, HF, W1, HF, agg_w, HF, agg_b,
      nullptr, nullptr, nullptr, nullptr, nullptr, W2, HF);
  // a = relu([h0|agg] @ attn_w1 + attn_b1)        -> W1
  gemm_kernel<16, 8, EPI_RELU><<<gblocks, b256, 0, stream>>>(
      W0, HF, W2, HF, attn_w1, HF, attn_b1,
      nullptr, nullptr, nullptr, nullptr, nullptr, W1, HF);
  // h_att = h0 + agg * sigmoid(a@w2+b2)           -> W1 (in place over a)
  attn_hatt_kernel<<<NN, b128, 0, stream>>>(W1, attn_w2, attn_b2, W0, W2, W1);

  // layer 0: spmm(W1)->W0 ; relu(BN(W0@gc0+b0))           -> W2
  spmm_kernel<true><<<NN, b128, 0, stream>>>(row_ptr, col, W1, inv_out, inv_in, W0);
  gemm_kernel<8, 8, EPI_BN><<<gblocks, b256, 0, stream>>>(
      W0, HF, nullptr, 0, gc_w, HF, gc_b,
      bn_gamma, bn_beta, bn_mean, bn_var, nullptr, W2, HF);
  // layer 1: spmm(W2)->W0 ; relu(BN(W0@gc1+b1)) + W2      -> W1
  spmm_kernel<true><<<NN, b128, 0, stream>>>(row_ptr, col, W2, inv_out, inv_in, W0);
  gemm_kernel<8, 8, EPI_BN_RES><<<gblocks, b256, 0, stream>>>(
      W0, HF, nullptr, 0, gc_w + HF * HF, HF, gc_b + HF,
      bn_gamma + HF, bn_beta + HF, bn_mean + HF, bn_var + HF, W2, W1, HF);
  // layer 2: spmm(W1)->W0 ; relu(BN(W0@gc2+b2)) + W1      -> W2
  spmm_kernel<true><<<NN, b128, 0, stream>>>(row_ptr, col, W1, inv_out, inv_in, W0);
  gemm_kernel<8, 8, EPI_BN_RES><<<gblocks, b256, 0, stream>>>(
      W0, HF, nullptr, 0, gc_w + 2 * HF * HF, HF, gc_b + 2 * HF,
      bn_gamma + 2 * HF, bn_beta + 2 * HF, bn_mean + 2 * HF, bn_var + 2 * HF, W1, W2, HF);

  // out = W2 @ out_w + out_b                      -> d_out
  gemm_kernel<8, 4, EPI_NONE><<<gblocks, b256, 0, stream>>>(
      W2, HF, nullptr, 0, out_w, CC, out_b,
      nullptr, nullptr, nullptr, nullptr, nullptr, out, CC);
}

// Round 2
// 722.762 us; speedup vs baseline: 1.2734x; 1.2734x over previous
//
#include <hip/hip_runtime.h>
#include <math.h>

constexpr int NN  = 50000;   // nodes
constexpr int EE  = 800000;  // edges
constexpr int INF_ = 256;    // input feat
constexpr int HF  = 128;     // hidden
constexpr int CC  = 50;      // classes
constexpr long NH = (long)NN * HF;
#define EPSV 1e-5f

enum { EPI_RELU = 0, EPI_NONE = 1, EPI_BN = 2, EPI_BN_RES = 3 };

typedef __attribute__((ext_vector_type(4))) float f32x4;
typedef __attribute__((ext_vector_type(8))) short bf16x8;

__device__ __forceinline__ ushort f2bf(float f) {
  union { float f; unsigned u; } v; v.f = f;
  unsigned r = (v.u + 0x7fffu + ((v.u >> 16) & 1u)) >> 16;  // RNE
  return (ushort)r;
}
__device__ __forceinline__ float bf2f(ushort u) {
  union { unsigned u; float f; } v; v.u = ((unsigned)u) << 16;
  return v.f;
}

// ---------------- graph preprocessing ----------------

__global__ void count_deg_kernel(const int* __restrict__ src, const int* __restrict__ dst,
                                 int* __restrict__ indeg, int* __restrict__ outdeg) {
  int e = blockIdx.x * 256 + threadIdx.x;
  if (e < EE) {
    atomicAdd(&indeg[dst[e]], 1);
    atomicAdd(&outdeg[src[e]], 1);
  }
}

__global__ void inv_kernel(const int* __restrict__ indeg, const int* __restrict__ outdeg,
                           float* __restrict__ inv_mean, float* __restrict__ inv_in,
                           float* __restrict__ inv_out) {
  int i = blockIdx.x * 256 + threadIdx.x;
  if (i < NN) {
    float di = fmaxf((float)indeg[i], 1.f);
    float dz = fmaxf((float)outdeg[i], 1.f);
    inv_mean[i] = 1.f / di;
    inv_in[i]  = rsqrtf(di);
    inv_out[i] = rsqrtf(dz);
  }
}

__global__ __launch_bounds__(256) void scan_block_kernel(const int* __restrict__ counts,
                                                         int* excl, int* bsum, int n) {
  __shared__ int sh[256];
  int i = blockIdx.x * 256 + threadIdx.x;
  int v = (i < n) ? counts[i] : 0;
  sh[threadIdx.x] = v;
  __syncthreads();
  #pragma unroll
  for (int off = 1; off < 256; off <<= 1) {
    int tv = (threadIdx.x >= off) ? sh[threadIdx.x - off] : 0;
    __syncthreads();
    sh[threadIdx.x] += tv;
    __syncthreads();
  }
  if (i < n) excl[i] = sh[threadIdx.x] - v;
  if (threadIdx.x == 255 && bsum) bsum[blockIdx.x] = sh[255];
}

__global__ void add_offsets_kernel(int* __restrict__ row_ptr, const int* __restrict__ bsum,
                                   int* __restrict__ cursor) {
  int i = blockIdx.x * 256 + threadIdx.x;
  if (i < NN) {
    int v = row_ptr[i] + bsum[blockIdx.x];
    row_ptr[i] = v;
    cursor[i]  = v;
  }
  if (i == NN) row_ptr[NN] = EE;
}

__global__ void fill_csr_kernel(const int* __restrict__ src, const int* __restrict__ dst,
                                int* __restrict__ cursor, int* __restrict__ col) {
  int e = blockIdx.x * 256 + threadIdx.x;
  if (e < EE) {
    int p = atomicAdd(&cursor[dst[e]], 1);
    col[p] = src[e];
  }
}

// ---------------- SpMM ----------------

template<bool SRC_SCALE>
__global__ __launch_bounds__(128) void spmm_kernel(
    const int* __restrict__ row_ptr, const int* __restrict__ cols,
    const float* __restrict__ x, const float* __restrict__ sscale,
    const float* __restrict__ dscale, float* __restrict__ out) {
  int node = blockIdx.x;
  int f = threadIdx.x;
  int e = row_ptr[node], end = row_ptr[node + 1];
  float acc = 0.f;
  for (; e < end; ++e) {
    int s = cols[e];
    float v = x[(long)s * HF + f];
    if (SRC_SCALE) v *= sscale[s];
    acc += v;
  }
  out[(long)node * HF + f] = acc * dscale[node];
}

// ---------------- attention gate + gated residual ----------------

__global__ __launch_bounds__(128) void attn_hatt_kernel(
    const float* a, const float* __restrict__ w2, const float* __restrict__ b2,
    const float* __restrict__ h0, const float* __restrict__ agg, float* hatt) {
  int r = blockIdx.x, f = threadIdx.x;
  long idx = (long)r * HF + f;
  float v = a[idx] * w2[f];
  #pragma unroll
  for (int off = 32; off >= 1; off >>= 1) v += __shfl_down(v, off, 64);
  __shared__ float red[2];
  if ((f & 63) == 0) red[f >> 6] = v;
  __syncthreads();
  float dot = red[0] + red[1] + b2[0];
  float s = 1.f / (1.f + __expf(-dot));
  hatt[idx] = h0[idx] + agg[idx] * s;
}

// ---------------- weight prepack: fp32 W[K][N] -> bf16 hi/lo MFMA fragments ----------------
// packed index: (((kc*NTpad + nt)*64 + lane)*8 + j), element = W[kc*32+(lane>>4)*8+j][nt*16+(lane&15)]

__global__ void prepack_kernel(const float* __restrict__ W, int N, int ldw, int NTpad,
                               ushort* __restrict__ hi, ushort* __restrict__ lo, int total) {
  int idx = blockIdx.x * 256 + threadIdx.x;
  if (idx >= total) return;
  int j    = idx & 7;
  int lane = (idx >> 3) & 63;
  int rest = idx >> 9;
  int nt = rest % NTpad;
  int kc = rest / NTpad;
  int k = kc * 32 + (lane >> 4) * 8 + j;
  int n = nt * 16 + (lane & 15);
  float w = (n < N) ? W[(long)k * ldw + n] : 0.f;
  ushort h = f2bf(w);
  hi[idx] = h;
  lo[idx] = f2bf(w - bf2f(h));
}

// ---------------- split-bf16 MFMA GEMM: out = epi( [A1|A2] @ W + bias ) ----------------
// K = KC*32 (A2 supplies k>=128 when KC==8). Block: 4 waves, each 32 rows x NT*16 cols.

template<int KC, int NT, int EPI>
__global__ __launch_bounds__(256) void mgemm_kernel(
    const float* __restrict__ A1, int lda1,
    const float* __restrict__ A2, int lda2,
    const ushort* __restrict__ Bhi, const ushort* __restrict__ Blo,
    const float* __restrict__ bias,
    const float* __restrict__ g, const float* __restrict__ be,
    const float* __restrict__ mu, const float* __restrict__ va,
    const float* __restrict__ res,
    float* __restrict__ out, int ldc, int Ncols) {
  const int t = threadIdx.x;
  const int lane = t & 63;
  const int wid = t >> 6;
  const int rowbase = blockIdx.x * 128 + wid * 32;
  const int arow0 = rowbase + (lane & 15);
  const int arow1 = arow0 + 16;
  const int kgrp = (lane >> 4) * 8;

  f32x4 acc[2][NT];
  #pragma unroll
  for (int r = 0; r < 2; ++r)
    #pragma unroll
    for (int n = 0; n < NT; ++n) acc[r][n] = (f32x4){0.f, 0.f, 0.f, 0.f};

  for (int kc = 0; kc < KC; ++kc) {
    const bool second = (KC == 8) && (kc >= 4);
    const float* Ap = second ? A2 : A1;
    const int lda = second ? lda2 : lda1;
    const long kb = (long)(second ? (kc - 4) * 32 : kc * 32) + kgrp;

    const f32x4 z4 = {0.f, 0.f, 0.f, 0.f};
    f32x4 av0a = z4, av0b = z4, av1a = z4, av1b = z4;
    if (arow0 < NN) {
      const float* p = Ap + (long)arow0 * lda + kb;
      av0a = *(const f32x4*)p;
      av0b = *(const f32x4*)(p + 4);
    }
    if (arow1 < NN) {
      const float* p = Ap + (long)arow1 * lda + kb;
      av1a = *(const f32x4*)p;
      av1b = *(const f32x4*)(p + 4);
    }

    bf16x8 ah0, al0, ah1, al1;
    #pragma unroll
    for (int j = 0; j < 8; ++j) {
      float v0 = (j < 4) ? av0a[j] : av0b[j - 4];
      ushort h0 = f2bf(v0);
      ah0[j] = (short)h0;
      al0[j] = (short)f2bf(v0 - bf2f(h0));
      float v1 = (j < 4) ? av1a[j] : av1b[j - 4];
      ushort h1 = f2bf(v1);
      ah1[j] = (short)h1;
      al1[j] = (short)f2bf(v1 - bf2f(h1));
    }

    const ushort* bh = Bhi + ((long)kc * NT * 64 + lane) * 8;
    const ushort* bl = Blo + ((long)kc * NT * 64 + lane) * 8;
    #pragma unroll
    for (int nt = 0; nt < NT; ++nt) {
      bf16x8 bhv = *(const bf16x8*)(bh + (long)nt * 512);
      bf16x8 blv = *(const bf16x8*)(bl + (long)nt * 512);
      acc[0][nt] = __builtin_amdgcn_mfma_f32_16x16x32_bf16(ah0, bhv, acc[0][nt], 0, 0, 0);
      acc[1][nt] = __builtin_amdgcn_mfma_f32_16x16x32_bf16(ah1, bhv, acc[1][nt], 0, 0, 0);
      acc[0][nt] = __builtin_amdgcn_mfma_f32_16x16x32_bf16(al0, bhv, acc[0][nt], 0, 0, 0);
      acc[1][nt] = __builtin_amdgcn_mfma_f32_16x16x32_bf16(al1, bhv, acc[1][nt], 0, 0, 0);
      acc[0][nt] = __builtin_amdgcn_mfma_f32_16x16x32_bf16(ah0, blv, acc[0][nt], 0, 0, 0);
      acc[1][nt] = __builtin_amdgcn_mfma_f32_16x16x32_bf16(ah1, blv, acc[1][nt], 0, 0, 0);
    }
  }

  const int colg = lane & 15;
  const int rsub = (lane >> 4) * 4;
  #pragma unroll
  for (int nt = 0; nt < NT; ++nt) {
    int c = nt * 16 + colg;
    if (c >= Ncols) continue;
    float bb = bias ? bias[c] : 0.f;
    float scale = 1.f, shift = 0.f;
    if (EPI == EPI_BN || EPI == EPI_BN_RES) {
      scale = g[c] * rsqrtf(va[c] + EPSV);
      shift = be[c] - mu[c] * scale;
    }
    #pragma unroll
    for (int rg = 0; rg < 2; ++rg) {
      #pragma unroll
      for (int i = 0; i < 4; ++i) {
        int r = rowbase + rg * 16 + rsub + i;
        if (r >= NN) continue;
        float v = acc[rg][nt][i] + bb;
        if (EPI == EPI_RELU) {
          v = fmaxf(v, 0.f);
        } else if (EPI == EPI_BN || EPI == EPI_BN_RES) {
          v = fmaxf(v * scale + shift, 0.f);
          if (EPI == EPI_BN_RES) v += res[(long)r * HF + c];
        }
        out[(long)r * ldc + c] = v;
      }
    }
  }
}

// ---------------- launch ----------------

extern "C" void kernel_launch(void* const* d_in, const int* in_sizes, int n_in,
                              void* d_out, int out_size, void* d_ws, size_t ws_size,
                              hipStream_t stream) {
  const float* features = (const float*)d_in[0];
  const int*   src      = (const int*)d_in[1];
  const int*   dst      = (const int*)d_in[2];
  const float* w_in     = (const float*)d_in[3];
  const float* b_in     = (const float*)d_in[4];
  const float* gc_w     = (const float*)d_in[5];
  const float* gc_b     = (const float*)d_in[6];
  const float* bn_gamma = (const float*)d_in[7];
  const float* bn_beta  = (const float*)d_in[8];
  const float* bn_mean  = (const float*)d_in[9];
  const float* bn_var   = (const float*)d_in[10];
  const float* attn_w1  = (const float*)d_in[11];
  const float* attn_b1  = (const float*)d_in[12];
  const float* attn_w2  = (const float*)d_in[13];
  const float* attn_b2  = (const float*)d_in[14];
  const float* agg_w    = (const float*)d_in[15];
  const float* agg_b    = (const float*)d_in[16];
  const float* out_w    = (const float*)d_in[17];
  const float* out_b    = (const float*)d_in[18];
  float* out = (float*)d_out;

  float* fbase   = (float*)d_ws;
  float* W0 = fbase;                 // h0 -> spmm scratch
  float* W1 = fbase + NH;            // neigh -> a -> h_att -> h(final)
  float* W2 = fbase + 2 * NH;        // agg -> h(L0) -> h(L2)
  float* inv_mean = fbase + 3 * NH;
  float* inv_in   = inv_mean + NN;
  float* inv_out  = inv_in + NN;
  int* indeg   = (int*)(inv_out + NN);
  int* outdeg  = indeg + NN;
  int* row_ptr = outdeg + NN;        // NN+1
  int* cursor  = row_ptr + NN + 1;
  int* bsum    = cursor + NN;        // 256
  int* col     = bsum + 256;         // EE

  // packed bf16 hi/lo weights
  ushort* pk = (ushort*)(col + EE);
  const int SZ256 = 8 * 8 * 512;     // K=256, NT=8
  const int SZ128 = 4 * 8 * 512;     // K=128, NT=8
  const int SZOUT = 4 * 4 * 512;     // K=128, NT=4
  ushort* win_hi = pk;  pk += SZ256;  ushort* win_lo = pk;  pk += SZ256;
  ushort* agg_hi = pk;  pk += SZ256;  ushort* agg_lo = pk;  pk += SZ256;
  ushort* at1_hi = pk;  pk += SZ256;  ushort* at1_lo = pk;  pk += SZ256;
  ushort* gch[3], *gcl[3];
  for (int i = 0; i < 3; ++i) { gch[i] = pk; pk += SZ128; gcl[i] = pk; pk += SZ128; }
  ushort* ow_hi = pk;  pk += SZOUT;   ushort* ow_lo = pk;  pk += SZOUT;

  dim3 b256(256), b128(128);
  const int gE = (EE + 255) / 256, gN = (NN + 255) / 256;
  const int gblocks = (NN + 127) / 128;

  // graph preprocessing
  hipMemsetAsync(indeg, 0, sizeof(int) * 2 * NN, stream);
  count_deg_kernel<<<gE, b256, 0, stream>>>(src, dst, indeg, outdeg);
  inv_kernel<<<gN, b256, 0, stream>>>(indeg, outdeg, inv_mean, inv_in, inv_out);
  scan_block_kernel<<<gN, b256, 0, stream>>>(indeg, row_ptr, bsum, NN);
  scan_block_kernel<<<1, b256, 0, stream>>>(bsum, bsum, nullptr, gN);
  add_offsets_kernel<<<gN, b256, 0, stream>>>(row_ptr, bsum, cursor);
  fill_csr_kernel<<<gE, b256, 0, stream>>>(src, dst, cursor, col);

  // weight prepack (independent of graph work)
  prepack_kernel<<<(SZ256 + 255) / 256, b256, 0, stream>>>(w_in,    HF, HF, 8, win_hi, win_lo, SZ256);
  prepack_kernel<<<(SZ256 + 255) / 256, b256, 0, stream>>>(agg_w,   HF, HF, 8, agg_hi, agg_lo, SZ256);
  prepack_kernel<<<(SZ256 + 255) / 256, b256, 0, stream>>>(attn_w1, HF, HF, 8, at1_hi, at1_lo, SZ256);
  for (int i = 0; i < 3; ++i)
    prepack_kernel<<<(SZ128 + 255) / 256, b256, 0, stream>>>(gc_w + (long)i * HF * HF, HF, HF, 8, gch[i], gcl[i], SZ128);
  prepack_kernel<<<(SZOUT + 255) / 256, b256, 0, stream>>>(out_w, CC, CC, 4, ow_hi, ow_lo, SZOUT);

  // h0 = relu(features @ w_in + b_in)            -> W0
  mgemm_kernel<8, 8, EPI_RELU><<<gblocks, b256, 0, stream>>>(
      features, INF_, features + 128, INF_, win_hi, win_lo, b_in,
      nullptr, nullptr, nullptr, nullptr, nullptr, W0, HF, HF);
  // neigh = mean-agg(h0)                          -> W1
  spmm_kernel<false><<<NN, b128, 0, stream>>>(row_ptr, col, W0, nullptr, inv_mean, W1);
  // agg = relu([h0|neigh] @ agg_w + agg_b)        -> W2
  mgemm_kernel<8, 8, EPI_RELU><<<gblocks, b256, 0, stream>>>(
      W0, HF, W1, HF, agg_hi, agg_lo, agg_b,
      nullptr, nullptr, nullptr, nullptr, nullptr, W2, HF, HF);
  // a = relu([h0|agg] @ attn_w1 + attn_b1)        -> W1
  mgemm_kernel<8, 8, EPI_RELU><<<gblocks, b256, 0, stream>>>(
      W0, HF, W2, HF, at1_hi, at1_lo, attn_b1,
      nullptr, nullptr, nullptr, nullptr, nullptr, W1, HF, HF);
  // h_att = h0 + agg * sigmoid(a@w2+b2)           -> W1 (in place over a)
  attn_hatt_kernel<<<NN, b128, 0, stream>>>(W1, attn_w2, attn_b2, W0, W2, W1);

  // layer 0: spmm(W1)->W0 ; relu(BN(W0@gc0+b0))           -> W2
  spmm_kernel<true><<<NN, b128, 0, stream>>>(row_ptr, col, W1, inv_out, inv_in, W0);
  mgemm_kernel<4, 8, EPI_BN><<<gblocks, b256, 0, stream>>>(
      W0, HF, nullptr, 0, gch[0], gcl[0], gc_b,
      bn_gamma, bn_beta, bn_mean, bn_var, nullptr, W2, HF, HF);
  // layer 1: spmm(W2)->W0 ; relu(BN(W0@gc1+b1)) + W2      -> W1
  spmm_kernel<true><<<NN, b128, 0, stream>>>(row_ptr, col, W2, inv_out, inv_in, W0);
  mgemm_kernel<4, 8, EPI_BN_RES><<<gblocks, b256, 0, stream>>>(
      W0, HF, nullptr, 0, gch[1], gcl[1], gc_b + HF,
      bn_gamma + HF, bn_beta + HF, bn_mean + HF, bn_var + HF, W2, W1, HF, HF);
  // layer 2: spmm(W1)->W0 ; relu(BN(W0@gc2+b2)) + W1      -> W2
  spmm_kernel<true><<<NN, b128, 0, stream>>>(row_ptr, col, W1, inv_out, inv_in, W0);
  mgemm_kernel<4, 8, EPI_BN_RES><<<gblocks, b256, 0, stream>>>(
      W0, HF, nullptr, 0, gch[2], gcl[2], gc_b + 2 * HF,
      bn_gamma + 2 * HF, bn_beta + 2 * HF, bn_mean + 2 * HF, bn_var + 2 * HF, W1, W2, HF, HF);

  // out = W2 @ out_w + out_b                      -> d_out
  mgemm_kernel<4, 4, EPI_NONE><<<gblocks, b256, 0, stream>>>(
      W2, HF, nullptr, 0, ow_hi, ow_lo, out_b,
      nullptr, nullptr, nullptr, nullptr, nullptr, out, CC, CC);
}

// Round 3
// 552.807 us; speedup vs baseline: 1.6649x; 1.3074x over previous
//
#include <hip/hip_runtime.h>
#include <hip/hip_fp16.h>
#include <math.h>

constexpr int NN  = 50000;   // nodes
constexpr int EE  = 800000;  // edges
constexpr int INF_ = 256;    // input feat
constexpr int HF  = 128;     // hidden
constexpr int CC  = 50;      // classes
constexpr long NH = (long)NN * HF;
#define EPSV 1e-5f

enum { EPI_RELU = 0, EPI_NONE = 1, EPI_BN = 2, EPI_BN_RES = 3 };
enum { H16_NONE = 0, H16_RAW = 1, H16_SCALED = 2 };

typedef __attribute__((ext_vector_type(4))) float f32x4;
typedef __attribute__((ext_vector_type(8))) short bf16x8;

__device__ __forceinline__ ushort f2bf(float f) {
  union { float f; unsigned u; } v; v.f = f;
  unsigned r = (v.u + 0x7fffu + ((v.u >> 16) & 1u)) >> 16;  // RNE
  return (ushort)r;
}
__device__ __forceinline__ float bf2f(ushort u) {
  union { unsigned u; float f; } v; v.u = ((unsigned)u) << 16;
  return v.f;
}

// ---------------- graph preprocessing ----------------

__global__ void count_deg_kernel(const int* __restrict__ src, const int* __restrict__ dst,
                                 int* __restrict__ indeg, int* __restrict__ outdeg) {
  int e = blockIdx.x * 256 + threadIdx.x;
  if (e < EE) {
    atomicAdd(&indeg[dst[e]], 1);
    atomicAdd(&outdeg[src[e]], 1);
  }
}

__global__ void inv_kernel(const int* __restrict__ indeg, const int* __restrict__ outdeg,
                           float* __restrict__ inv_mean, float* __restrict__ inv_in,
                           float* __restrict__ inv_out) {
  int i = blockIdx.x * 256 + threadIdx.x;
  if (i < NN) {
    float di = fmaxf((float)indeg[i], 1.f);
    float dz = fmaxf((float)outdeg[i], 1.f);
    inv_mean[i] = 1.f / di;
    inv_in[i]  = rsqrtf(di);
    inv_out[i] = rsqrtf(dz);
  }
}

__global__ __launch_bounds__(256) void scan_block_kernel(const int* __restrict__ counts,
                                                         int* excl, int* bsum, int n) {
  __shared__ int sh[256];
  int i = blockIdx.x * 256 + threadIdx.x;
  int v = (i < n) ? counts[i] : 0;
  sh[threadIdx.x] = v;
  __syncthreads();
  #pragma unroll
  for (int off = 1; off < 256; off <<= 1) {
    int tv = (threadIdx.x >= off) ? sh[threadIdx.x - off] : 0;
    __syncthreads();
    sh[threadIdx.x] += tv;
    __syncthreads();
  }
  if (i < n) excl[i] = sh[threadIdx.x] - v;
  if (threadIdx.x == 255 && bsum) bsum[blockIdx.x] = sh[255];
}

__global__ void add_offsets_kernel(int* __restrict__ row_ptr, const int* __restrict__ bsum,
                                   int* __restrict__ cursor) {
  int i = blockIdx.x * 256 + threadIdx.x;
  if (i < NN) {
    int v = row_ptr[i] + bsum[blockIdx.x];
    row_ptr[i] = v;
    cursor[i]  = v;
  }
  if (i == NN) row_ptr[NN] = EE;
}

__global__ void fill_csr_kernel(const int* __restrict__ src, const int* __restrict__ dst,
                                int* __restrict__ cursor, int* __restrict__ col) {
  int e = blockIdx.x * 256 + threadIdx.x;
  if (e < EE) {
    int p = atomicAdd(&cursor[dst[e]], 1);
    col[p] = src[e];
  }
}

// ---------------- SpMM (fp16 gather, wave per node, 4-deep MLP) ----------------
// out[node] = dscale[node] * sum_{e in CSR row} x16[cols[e]]   (x16 pre-scaled by producer)

__global__ __launch_bounds__(256) void spmm16_kernel(
    const int* __restrict__ row_ptr, const int* __restrict__ cols,
    const __half2* __restrict__ x, const float* __restrict__ dscale,
    float* __restrict__ out) {
  const int lane = threadIdx.x & 63;
  const int node = blockIdx.x * 4 + (threadIdx.x >> 6);
  if (node >= NN) return;
  int e = row_ptr[node];
  const int end = row_ptr[node + 1];
  float ax = 0.f, ay = 0.f;
  for (; e + 4 <= end; e += 4) {
    int s0 = cols[e + 0], s1 = cols[e + 1], s2 = cols[e + 2], s3 = cols[e + 3];
    __half2 v0 = x[(long)s0 * 64 + lane];
    __half2 v1 = x[(long)s1 * 64 + lane];
    __half2 v2 = x[(long)s2 * 64 + lane];
    __half2 v3 = x[(long)s3 * 64 + lane];
    float2 f0 = __half22float2(v0), f1 = __half22float2(v1);
    float2 f2 = __half22float2(v2), f3 = __half22float2(v3);
    ax += (f0.x + f1.x) + (f2.x + f3.x);
    ay += (f0.y + f1.y) + (f2.y + f3.y);
  }
  for (; e < end; ++e) {
    float2 f = __half22float2(x[(long)cols[e] * 64 + lane]);
    ax += f.x; ay += f.y;
  }
  const float d = dscale[node];
  *(float2*)&out[(long)node * HF + lane * 2] = make_float2(ax * d, ay * d);
}

// ---------------- attention gate + gated residual ----------------

__global__ __launch_bounds__(128) void attn_hatt_kernel(
    const float* a, const float* __restrict__ w2, const float* __restrict__ b2,
    const float* __restrict__ h0, const float* __restrict__ agg,
    const float* __restrict__ inv_out,
    float* hatt, __half* __restrict__ hatt16) {
  int r = blockIdx.x, f = threadIdx.x;
  long idx = (long)r * HF + f;
  float v = a[idx] * w2[f];
  #pragma unroll
  for (int off = 32; off >= 1; off >>= 1) v += __shfl_down(v, off, 64);
  __shared__ float red[2];
  if ((f & 63) == 0) red[f >> 6] = v;
  __syncthreads();
  float dot = red[0] + red[1] + b2[0];
  float s = 1.f / (1.f + __expf(-dot));
  float h = h0[idx] + agg[idx] * s;
  hatt[idx] = h;
  hatt16[idx] = __float2half(h * inv_out[r]);
}

// ---------------- weight prepack: fp32 W[K][N] -> bf16 hi/lo MFMA fragments ----------------

__global__ void prepack_kernel(const float* __restrict__ W, int N, int ldw, int NTpad,
                               ushort* __restrict__ hi, ushort* __restrict__ lo, int total) {
  int idx = blockIdx.x * 256 + threadIdx.x;
  if (idx >= total) return;
  int j    = idx & 7;
  int lane = (idx >> 3) & 63;
  int rest = idx >> 9;
  int nt = rest % NTpad;
  int kc = rest / NTpad;
  int k = kc * 32 + (lane >> 4) * 8 + j;
  int n = nt * 16 + (lane & 15);
  float w = (n < N) ? W[(long)k * ldw + n] : 0.f;
  ushort h = f2bf(w);
  hi[idx] = h;
  lo[idx] = f2bf(w - bf2f(h));
}

// ---------------- split-bf16 MFMA GEMM: out = epi( [A1|A2] @ W + bias ) ----------------

template<int KC, int NT, int EPI, int H16>
__global__ __launch_bounds__(256) void mgemm_kernel(
    const float* __restrict__ A1, int lda1,
    const float* __restrict__ A2, int lda2,
    const ushort* __restrict__ Bhi, const ushort* __restrict__ Blo,
    const float* __restrict__ bias,
    const float* __restrict__ g, const float* __restrict__ be,
    const float* __restrict__ mu, const float* __restrict__ va,
    const float* __restrict__ res,
    float* __restrict__ out, int ldc, int Ncols,
    __half* __restrict__ out16, const float* __restrict__ rowscale) {
  const int t = threadIdx.x;
  const int lane = t & 63;
  const int wid = t >> 6;
  const int rowbase = blockIdx.x * 128 + wid * 32;
  const int arow0 = rowbase + (lane & 15);
  const int arow1 = arow0 + 16;
  const int kgrp = (lane >> 4) * 8;

  f32x4 acc[2][NT];
  #pragma unroll
  for (int r = 0; r < 2; ++r)
    #pragma unroll
    for (int n = 0; n < NT; ++n) acc[r][n] = (f32x4){0.f, 0.f, 0.f, 0.f};

  for (int kc = 0; kc < KC; ++kc) {
    const bool second = (KC == 8) && (kc >= 4);
    const float* Ap = second ? A2 : A1;
    const int lda = second ? lda2 : lda1;
    const long kb = (long)(second ? (kc - 4) * 32 : kc * 32) + kgrp;

    const f32x4 z4 = {0.f, 0.f, 0.f, 0.f};
    f32x4 av0a = z4, av0b = z4, av1a = z4, av1b = z4;
    if (arow0 < NN) {
      const float* p = Ap + (long)arow0 * lda + kb;
      av0a = *(const f32x4*)p;
      av0b = *(const f32x4*)(p + 4);
    }
    if (arow1 < NN) {
      const float* p = Ap + (long)arow1 * lda + kb;
      av1a = *(const f32x4*)p;
      av1b = *(const f32x4*)(p + 4);
    }

    bf16x8 ah0, al0, ah1, al1;
    #pragma unroll
    for (int j = 0; j < 8; ++j) {
      float v0 = (j < 4) ? av0a[j] : av0b[j - 4];
      ushort h0 = f2bf(v0);
      ah0[j] = (short)h0;
      al0[j] = (short)f2bf(v0 - bf2f(h0));
      float v1 = (j < 4) ? av1a[j] : av1b[j - 4];
      ushort h1 = f2bf(v1);
      ah1[j] = (short)h1;
      al1[j] = (short)f2bf(v1 - bf2f(h1));
    }

    const ushort* bh = Bhi + ((long)kc * NT * 64 + lane) * 8;
    const ushort* bl = Blo + ((long)kc * NT * 64 + lane) * 8;
    #pragma unroll
    for (int nt = 0; nt < NT; ++nt) {
      bf16x8 bhv = *(const bf16x8*)(bh + (long)nt * 512);
      bf16x8 blv = *(const bf16x8*)(bl + (long)nt * 512);
      acc[0][nt] = __builtin_amdgcn_mfma_f32_16x16x32_bf16(ah0, bhv, acc[0][nt], 0, 0, 0);
      acc[1][nt] = __builtin_amdgcn_mfma_f32_16x16x32_bf16(ah1, bhv, acc[1][nt], 0, 0, 0);
      acc[0][nt] = __builtin_amdgcn_mfma_f32_16x16x32_bf16(al0, bhv, acc[0][nt], 0, 0, 0);
      acc[1][nt] = __builtin_amdgcn_mfma_f32_16x16x32_bf16(al1, bhv, acc[1][nt], 0, 0, 0);
      acc[0][nt] = __builtin_amdgcn_mfma_f32_16x16x32_bf16(ah0, blv, acc[0][nt], 0, 0, 0);
      acc[1][nt] = __builtin_amdgcn_mfma_f32_16x16x32_bf16(ah1, blv, acc[1][nt], 0, 0, 0);
    }
  }

  const int colg = lane & 15;
  const int rsub = (lane >> 4) * 4;
  #pragma unroll
  for (int nt = 0; nt < NT; ++nt) {
    int c = nt * 16 + colg;
    if (c >= Ncols) continue;
    float bb = bias ? bias[c] : 0.f;
    float scale = 1.f, shift = 0.f;
    if (EPI == EPI_BN || EPI == EPI_BN_RES) {
      scale = g[c] * rsqrtf(va[c] + EPSV);
      shift = be[c] - mu[c] * scale;
    }
    #pragma unroll
    for (int rg = 0; rg < 2; ++rg) {
      #pragma unroll
      for (int i = 0; i < 4; ++i) {
        int r = rowbase + rg * 16 + rsub + i;
        if (r >= NN) continue;
        float v = acc[rg][nt][i] + bb;
        if (EPI == EPI_RELU) {
          v = fmaxf(v, 0.f);
        } else if (EPI == EPI_BN || EPI == EPI_BN_RES) {
          v = fmaxf(v * scale + shift, 0.f);
          if (EPI == EPI_BN_RES) v += res[(long)r * HF + c];
        }
        out[(long)r * ldc + c] = v;
        if (H16 != H16_NONE) {
          float sc = (H16 == H16_SCALED) ? rowscale[r] : 1.f;
          out16[(long)r * HF + c] = __float2half(v * sc);
        }
      }
    }
  }
}

// ---------------- launch ----------------

extern "C" void kernel_launch(void* const* d_in, const int* in_sizes, int n_in,
                              void* d_out, int out_size, void* d_ws, size_t ws_size,
                              hipStream_t stream) {
  const float* features = (const float*)d_in[0];
  const int*   src      = (const int*)d_in[1];
  const int*   dst      = (const int*)d_in[2];
  const float* w_in     = (const float*)d_in[3];
  const float* b_in     = (const float*)d_in[4];
  const float* gc_w     = (const float*)d_in[5];
  const float* gc_b     = (const float*)d_in[6];
  const float* bn_gamma = (const float*)d_in[7];
  const float* bn_beta  = (const float*)d_in[8];
  const float* bn_mean  = (const float*)d_in[9];
  const float* bn_var   = (const float*)d_in[10];
  const float* attn_w1  = (const float*)d_in[11];
  const float* attn_b1  = (const float*)d_in[12];
  const float* attn_w2  = (const float*)d_in[13];
  const float* attn_b2  = (const float*)d_in[14];
  const float* agg_w    = (const float*)d_in[15];
  const float* agg_b    = (const float*)d_in[16];
  const float* out_w    = (const float*)d_in[17];
  const float* out_b    = (const float*)d_in[18];
  float* out = (float*)d_out;

  float* fbase   = (float*)d_ws;
  float* W0 = fbase;                 // h0 -> spmm scratch
  float* W1 = fbase + NH;            // neigh -> a -> h_att -> h(final)
  float* W2 = fbase + 2 * NH;        // agg -> h(L0) -> h(L2)
  float* inv_mean = fbase + 3 * NH;
  float* inv_in   = inv_mean + NN;
  float* inv_out  = inv_in + NN;
  int* indeg   = (int*)(inv_out + NN);
  int* outdeg  = indeg + NN;
  int* row_ptr = outdeg + NN;        // NN+1
  int* cursor  = row_ptr + NN + 1;
  int* bsum    = cursor + NN;        // 256
  int* col     = bsum + 256;         // EE

  // packed bf16 hi/lo weights
  ushort* pk = (ushort*)(col + EE);
  const int SZ256 = 8 * 8 * 512;     // K=256, NT=8
  const int SZ128 = 4 * 8 * 512;     // K=128, NT=8
  const int SZOUT = 4 * 4 * 512;     // K=128, NT=4
  ushort* win_hi = pk;  pk += SZ256;  ushort* win_lo = pk;  pk += SZ256;
  ushort* agg_hi = pk;  pk += SZ256;  ushort* agg_lo = pk;  pk += SZ256;
  ushort* at1_hi = pk;  pk += SZ256;  ushort* at1_lo = pk;  pk += SZ256;
  ushort* gch[3], *gcl[3];
  for (int i = 0; i < 3; ++i) { gch[i] = pk; pk += SZ128; gcl[i] = pk; pk += SZ128; }
  ushort* ow_hi = pk;  pk += SZOUT;   ushort* ow_lo = pk;  pk += SZOUT;
  __half* X16 = (__half*)pk;          // NH halfs (fp16 gather rows, reused per stage)

  dim3 b256(256), b128(128);
  const int gE = (EE + 255) / 256, gN = (NN + 255) / 256;
  const int gblocks = (NN + 127) / 128;
  const int gspmm = (NN + 3) / 4;

  // graph preprocessing
  hipMemsetAsync(indeg, 0, sizeof(int) * 2 * NN, stream);
  count_deg_kernel<<<gE, b256, 0, stream>>>(src, dst, indeg, outdeg);
  inv_kernel<<<gN, b256, 0, stream>>>(indeg, outdeg, inv_mean, inv_in, inv_out);
  scan_block_kernel<<<gN, b256, 0, stream>>>(indeg, row_ptr, bsum, NN);
  scan_block_kernel<<<1, b256, 0, stream>>>(bsum, bsum, nullptr, gN);
  add_offsets_kernel<<<gN, b256, 0, stream>>>(row_ptr, bsum, cursor);
  fill_csr_kernel<<<gE, b256, 0, stream>>>(src, dst, cursor, col);

  // weight prepack
  prepack_kernel<<<(SZ256 + 255) / 256, b256, 0, stream>>>(w_in,    HF, HF, 8, win_hi, win_lo, SZ256);
  prepack_kernel<<<(SZ256 + 255) / 256, b256, 0, stream>>>(agg_w,   HF, HF, 8, agg_hi, agg_lo, SZ256);
  prepack_kernel<<<(SZ256 + 255) / 256, b256, 0, stream>>>(attn_w1, HF, HF, 8, at1_hi, at1_lo, SZ256);
  for (int i = 0; i < 3; ++i)
    prepack_kernel<<<(SZ128 + 255) / 256, b256, 0, stream>>>(gc_w + (long)i * HF * HF, HF, HF, 8, gch[i], gcl[i], SZ128);
  prepack_kernel<<<(SZOUT + 255) / 256, b256, 0, stream>>>(out_w, CC, CC, 4, ow_hi, ow_lo, SZOUT);

  // h0 = relu(features @ w_in + b_in)            -> W0 (+fp16 raw -> X16)
  mgemm_kernel<8, 8, EPI_RELU, H16_RAW><<<gblocks, b256, 0, stream>>>(
      features, INF_, features + 128, INF_, win_hi, win_lo, b_in,
      nullptr, nullptr, nullptr, nullptr, nullptr, W0, HF, HF, X16, nullptr);
  // neigh = mean-agg(h0)                          -> W1
  spmm16_kernel<<<gspmm, b256, 0, stream>>>(row_ptr, col, (const __half2*)X16, inv_mean, W1);
  // agg = relu([h0|neigh] @ agg_w + agg_b)        -> W2
  mgemm_kernel<8, 8, EPI_RELU, H16_NONE><<<gblocks, b256, 0, stream>>>(
      W0, HF, W1, HF, agg_hi, agg_lo, agg_b,
      nullptr, nullptr, nullptr, nullptr, nullptr, W2, HF, HF, nullptr, nullptr);
  // a = relu([h0|agg] @ attn_w1 + attn_b1)        -> W1
  mgemm_kernel<8, 8, EPI_RELU, H16_NONE><<<gblocks, b256, 0, stream>>>(
      W0, HF, W2, HF, at1_hi, at1_lo, attn_b1,
      nullptr, nullptr, nullptr, nullptr, nullptr, W1, HF, HF, nullptr, nullptr);
  // h_att = h0 + agg * sigmoid(a@w2+b2)           -> W1 (+fp16 *inv_out -> X16)
  attn_hatt_kernel<<<NN, b128, 0, stream>>>(W1, attn_w2, attn_b2, W0, W2, inv_out, W1, X16);

  // layer 0: spmm(X16)->W0 ; relu(BN(W0@gc0+b0))          -> W2 (+fp16 -> X16)
  spmm16_kernel<<<gspmm, b256, 0, stream>>>(row_ptr, col, (const __half2*)X16, inv_in, W0);
  mgemm_kernel<4, 8, EPI_BN, H16_SCALED><<<gblocks, b256, 0, stream>>>(
      W0, HF, nullptr, 0, gch[0], gcl[0], gc_b,
      bn_gamma, bn_beta, bn_mean, bn_var, nullptr, W2, HF, HF, X16, inv_out);
  // layer 1: spmm(X16)->W0 ; relu(BN(W0@gc1+b1)) + W2     -> W1 (+fp16 -> X16)
  spmm16_kernel<<<gspmm, b256, 0, stream>>>(row_ptr, col, (const __half2*)X16, inv_in, W0);
  mgemm_kernel<4, 8, EPI_BN_RES, H16_SCALED><<<gblocks, b256, 0, stream>>>(
      W0, HF, nullptr, 0, gch[1], gcl[1], gc_b + HF,
      bn_gamma + HF, bn_beta + HF, bn_mean + HF, bn_var + HF, W2, W1, HF, HF, X16, inv_out);
  // layer 2: spmm(X16)->W0 ; relu(BN(W0@gc2+b2)) + W1     -> W2
  spmm16_kernel<<<gspmm, b256, 0, stream>>>(row_ptr, col, (const __half2*)X16, inv_in, W0);
  mgemm_kernel<4, 8, EPI_BN_RES, H16_NONE><<<gblocks, b256, 0, stream>>>(
      W0, HF, nullptr, 0, gch[2], gcl[2], gc_b + 2 * HF,
      bn_gamma + 2 * HF, bn_beta + 2 * HF, bn_mean + 2 * HF, bn_var + 2 * HF, W1, W2, HF, HF,
      nullptr, nullptr);

  // out = W2 @ out_w + out_b                      -> d_out
  mgemm_kernel<4, 4, EPI_NONE, H16_NONE><<<gblocks, b256, 0, stream>>>(
      W2, HF, nullptr, 0, ow_hi, ow_lo, out_b,
      nullptr, nullptr, nullptr, nullptr, nullptr, out, CC, CC, nullptr, nullptr);
}

// Round 4
// 545.768 us; speedup vs baseline: 1.6864x; 1.0129x over previous
//
#include <hip/hip_runtime.h>
#include <hip/hip_fp16.h>
#include <math.h>

constexpr int NN  = 50000;   // nodes
constexpr int EE  = 800000;  // edges
constexpr int INF_ = 256;    // input feat
constexpr int HF  = 128;     // hidden
constexpr int CC  = 50;      // classes
constexpr long NH = (long)NN * HF;
constexpr int NX = 8;        // XCDs
#define EPSV 1e-5f

enum { EPI_RELU = 0, EPI_NONE = 1, EPI_BN = 2, EPI_BN_RES = 3 };
enum { H16_NONE = 0, H16_RAW = 1, H16_SCALED = 2 };

typedef __attribute__((ext_vector_type(4))) float f32x4;
typedef __attribute__((ext_vector_type(8))) short bf16x8;

__device__ __forceinline__ ushort f2bf(float f) {
  union { float f; unsigned u; } v; v.f = f;
  unsigned r = (v.u + 0x7fffu + ((v.u >> 16) & 1u)) >> 16;  // RNE
  return (ushort)r;
}
__device__ __forceinline__ float bf2f(ushort u) {
  union { unsigned u; float f; } v; v.u = ((unsigned)u) << 16;
  return v.f;
}

__device__ __forceinline__ int get_xcc() {
  unsigned v;
  asm("s_getreg_b32 %0, hwreg(HW_REG_XCC_ID)" : "=s"(v));
  return (int)(v & 7u);
}

__device__ __forceinline__ unsigned wg_atomic_inc(unsigned* p) {
  return __hip_atomic_fetch_add(p, 1u, __ATOMIC_RELAXED, __HIP_MEMORY_SCOPE_WORKGROUP);
}

// ---------------- graph preprocessing (XCD-local L2 atomics) ----------------

__global__ __launch_bounds__(256) void count_deg_xcd_kernel(
    const int4* __restrict__ src4, const int4* __restrict__ dst4,
    unsigned* __restrict__ histS, unsigned* __restrict__ histD) {
  int i = blockIdx.x * 256 + threadIdx.x;
  const int x = get_xcc();
  unsigned* hS = histS + (long)x * NN;
  unsigned* hD = histD + (long)x * NN;
  if (i < EE / 4) {
    int4 d = dst4[i], s = src4[i];
    wg_atomic_inc(&hD[d.x]); wg_atomic_inc(&hD[d.y]);
    wg_atomic_inc(&hD[d.z]); wg_atomic_inc(&hD[d.w]);
    wg_atomic_inc(&hS[s.x]); wg_atomic_inc(&hS[s.y]);
    wg_atomic_inc(&hS[s.z]); wg_atomic_inc(&hS[s.w]);
  }
}

__global__ __launch_bounds__(256) void reduce_deg_kernel(
    const unsigned* __restrict__ histD, const unsigned* __restrict__ histS,
    int* __restrict__ indeg, float* __restrict__ inv_mean,
    float* __restrict__ inv_in, float* __restrict__ inv_out) {
  int i = blockIdx.x * 256 + threadIdx.x;
  if (i >= NN) return;
  unsigned di = 0, dz = 0;
  #pragma unroll
  for (int x = 0; x < NX; ++x) { di += histD[(long)x * NN + i]; dz += histS[(long)x * NN + i]; }
  indeg[i] = (int)di;
  float fdi = fmaxf((float)di, 1.f), fdz = fmaxf((float)dz, 1.f);
  inv_mean[i] = 1.f / fdi;
  inv_in[i]  = rsqrtf(fdi);
  inv_out[i] = rsqrtf(fdz);
}

__global__ __launch_bounds__(256) void scan_block_kernel(const int* __restrict__ counts,
                                                         int* excl, int* bsum, int n) {
  __shared__ int sh[256];
  int i = blockIdx.x * 256 + threadIdx.x;
  int v = (i < n) ? counts[i] : 0;
  sh[threadIdx.x] = v;
  __syncthreads();
  #pragma unroll
  for (int off = 1; off < 256; off <<= 1) {
    int tv = (threadIdx.x >= off) ? sh[threadIdx.x - off] : 0;
    __syncthreads();
    sh[threadIdx.x] += tv;
    __syncthreads();
  }
  if (i < n) excl[i] = sh[threadIdx.x] - v;
  if (threadIdx.x == 255 && bsum) bsum[blockIdx.x] = sh[255];
}

__global__ void add_offsets_kernel(int* __restrict__ row_ptr, const int* __restrict__ bsum,
                                   const unsigned* __restrict__ histD,
                                   unsigned* __restrict__ cursor) {
  int i = blockIdx.x * 256 + threadIdx.x;
  if (i < NN) {
    int v = row_ptr[i] + bsum[blockIdx.x];
    row_ptr[i] = v;
    unsigned run = (unsigned)v;
    #pragma unroll
    for (int x = 0; x < NX; ++x) {
      cursor[(long)x * NN + i] = run;
      run += histD[(long)x * NN + i];
    }
  }
  if (i == NN) row_ptr[NN] = EE;
}

__global__ __launch_bounds__(256) void fill_csr_xcd_kernel(
    const int4* __restrict__ src4, const int4* __restrict__ dst4,
    unsigned* __restrict__ cursor, int* __restrict__ col) {
  int i = blockIdx.x * 256 + threadIdx.x;
  const int x = get_xcc();
  unsigned* cur = cursor + (long)x * NN;
  if (i < EE / 4) {
    int4 d = dst4[i], s = src4[i];
    col[wg_atomic_inc(&cur[d.x])] = s.x;
    col[wg_atomic_inc(&cur[d.y])] = s.y;
    col[wg_atomic_inc(&cur[d.z])] = s.z;
    col[wg_atomic_inc(&cur[d.w])] = s.w;
  }
}

// ---------------- SpMM (fp16 gather, wave per node, 8-deep MLP) ----------------

__global__ __launch_bounds__(256) void spmm16_kernel(
    const int* __restrict__ row_ptr, const int* __restrict__ cols,
    const __half2* __restrict__ x, const float* __restrict__ dscale,
    float* __restrict__ out) {
  const int lane = threadIdx.x & 63;
  const int node = blockIdx.x * 4 + (threadIdx.x >> 6);
  if (node >= NN) return;
  int e = row_ptr[node];
  const int end = row_ptr[node + 1];
  float ax = 0.f, ay = 0.f;
  for (; e + 8 <= end; e += 8) {
    int s0 = cols[e + 0], s1 = cols[e + 1], s2 = cols[e + 2], s3 = cols[e + 3];
    int s4 = cols[e + 4], s5 = cols[e + 5], s6 = cols[e + 6], s7 = cols[e + 7];
    __half2 v0 = x[(long)s0 * 64 + lane];
    __half2 v1 = x[(long)s1 * 64 + lane];
    __half2 v2 = x[(long)s2 * 64 + lane];
    __half2 v3 = x[(long)s3 * 64 + lane];
    __half2 v4 = x[(long)s4 * 64 + lane];
    __half2 v5 = x[(long)s5 * 64 + lane];
    __half2 v6 = x[(long)s6 * 64 + lane];
    __half2 v7 = x[(long)s7 * 64 + lane];
    float2 f0 = __half22float2(v0), f1 = __half22float2(v1);
    float2 f2 = __half22float2(v2), f3 = __half22float2(v3);
    float2 f4 = __half22float2(v4), f5 = __half22float2(v5);
    float2 f6 = __half22float2(v6), f7 = __half22float2(v7);
    ax += ((f0.x + f1.x) + (f2.x + f3.x)) + ((f4.x + f5.x) + (f6.x + f7.x));
    ay += ((f0.y + f1.y) + (f2.y + f3.y)) + ((f4.y + f5.y) + (f6.y + f7.y));
  }
  for (; e + 4 <= end; e += 4) {
    int s0 = cols[e + 0], s1 = cols[e + 1], s2 = cols[e + 2], s3 = cols[e + 3];
    __half2 v0 = x[(long)s0 * 64 + lane];
    __half2 v1 = x[(long)s1 * 64 + lane];
    __half2 v2 = x[(long)s2 * 64 + lane];
    __half2 v3 = x[(long)s3 * 64 + lane];
    float2 f0 = __half22float2(v0), f1 = __half22float2(v1);
    float2 f2 = __half22float2(v2), f3 = __half22float2(v3);
    ax += (f0.x + f1.x) + (f2.x + f3.x);
    ay += (f0.y + f1.y) + (f2.y + f3.y);
  }
  for (; e < end; ++e) {
    float2 f = __half22float2(x[(long)cols[e] * 64 + lane]);
    ax += f.x; ay += f.y;
  }
  const float d = dscale[node];
  *(float2*)&out[(long)node * HF + lane * 2] = make_float2(ax * d, ay * d);
}

// ---------------- attention gate + gated residual ----------------

__global__ __launch_bounds__(128) void attn_hatt_kernel(
    const float* a, const float* __restrict__ w2, const float* __restrict__ b2,
    const float* __restrict__ h0, const float* __restrict__ agg,
    const float* __restrict__ inv_out,
    float* hatt, __half* __restrict__ hatt16) {
  int r = blockIdx.x, f = threadIdx.x;
  long idx = (long)r * HF + f;
  float v = a[idx] * w2[f];
  #pragma unroll
  for (int off = 32; off >= 1; off >>= 1) v += __shfl_down(v, off, 64);
  __shared__ float red[2];
  if ((f & 63) == 0) red[f >> 6] = v;
  __syncthreads();
  float dot = red[0] + red[1] + b2[0];
  float s = 1.f / (1.f + __expf(-dot));
  float h = h0[idx] + agg[idx] * s;
  hatt[idx] = h;
  hatt16[idx] = __float2half(h * inv_out[r]);
}

// ---------------- weight prepack: fp32 W[K][N] -> bf16 hi/lo MFMA fragments ----------------

__global__ void prepack_kernel(const float* __restrict__ W, int N, int ldw, int NTpad,
                               ushort* __restrict__ hi, ushort* __restrict__ lo, int total) {
  int idx = blockIdx.x * 256 + threadIdx.x;
  if (idx >= total) return;
  int j    = idx & 7;
  int lane = (idx >> 3) & 63;
  int rest = idx >> 9;
  int nt = rest % NTpad;
  int kc = rest / NTpad;
  int k = kc * 32 + (lane >> 4) * 8 + j;
  int n = nt * 16 + (lane & 15);
  float w = (n < N) ? W[(long)k * ldw + n] : 0.f;
  ushort h = f2bf(w);
  hi[idx] = h;
  lo[idx] = f2bf(w - bf2f(h));
}

// ---------------- split-bf16 MFMA GEMM: out = epi( [A1|A2] @ W + bias ) ----------------

template<int KC, int NT, int EPI, int H16>
__global__ __launch_bounds__(256) void mgemm_kernel(
    const float* __restrict__ A1, int lda1,
    const float* __restrict__ A2, int lda2,
    const ushort* __restrict__ Bhi, const ushort* __restrict__ Blo,
    const float* __restrict__ bias,
    const float* __restrict__ g, const float* __restrict__ be,
    const float* __restrict__ mu, const float* __restrict__ va,
    const float* __restrict__ res,
    float* __restrict__ out, int ldc, int Ncols,
    __half* __restrict__ out16, const float* __restrict__ rowscale) {
  const int t = threadIdx.x;
  const int lane = t & 63;
  const int wid = t >> 6;
  const int rowbase = blockIdx.x * 128 + wid * 32;
  const int arow0 = rowbase + (lane & 15);
  const int arow1 = arow0 + 16;
  const int kgrp = (lane >> 4) * 8;

  f32x4 acc[2][NT];
  #pragma unroll
  for (int r = 0; r < 2; ++r)
    #pragma unroll
    for (int n = 0; n < NT; ++n) acc[r][n] = (f32x4){0.f, 0.f, 0.f, 0.f};

  for (int kc = 0; kc < KC; ++kc) {
    const bool second = (KC == 8) && (kc >= 4);
    const float* Ap = second ? A2 : A1;
    const int lda = second ? lda2 : lda1;
    const long kb = (long)(second ? (kc - 4) * 32 : kc * 32) + kgrp;

    const f32x4 z4 = {0.f, 0.f, 0.f, 0.f};
    f32x4 av0a = z4, av0b = z4, av1a = z4, av1b = z4;
    if (arow0 < NN) {
      const float* p = Ap + (long)arow0 * lda + kb;
      av0a = *(const f32x4*)p;
      av0b = *(const f32x4*)(p + 4);
    }
    if (arow1 < NN) {
      const float* p = Ap + (long)arow1 * lda + kb;
      av1a = *(const f32x4*)p;
      av1b = *(const f32x4*)(p + 4);
    }

    bf16x8 ah0, al0, ah1, al1;
    #pragma unroll
    for (int j = 0; j < 8; ++j) {
      float v0 = (j < 4) ? av0a[j] : av0b[j - 4];
      ushort h0 = f2bf(v0);
      ah0[j] = (short)h0;
      al0[j] = (short)f2bf(v0 - bf2f(h0));
      float v1 = (j < 4) ? av1a[j] : av1b[j - 4];
      ushort h1 = f2bf(v1);
      ah1[j] = (short)h1;
      al1[j] = (short)f2bf(v1 - bf2f(h1));
    }

    const ushort* bh = Bhi + ((long)kc * NT * 64 + lane) * 8;
    const ushort* bl = Blo + ((long)kc * NT * 64 + lane) * 8;
    #pragma unroll
    for (int nt = 0; nt < NT; ++nt) {
      bf16x8 bhv = *(const bf16x8*)(bh + (long)nt * 512);
      bf16x8 blv = *(const bf16x8*)(bl + (long)nt * 512);
      acc[0][nt] = __builtin_amdgcn_mfma_f32_16x16x32_bf16(ah0, bhv, acc[0][nt], 0, 0, 0);
      acc[1][nt] = __builtin_amdgcn_mfma_f32_16x16x32_bf16(ah1, bhv, acc[1][nt], 0, 0, 0);
      acc[0][nt] = __builtin_amdgcn_mfma_f32_16x16x32_bf16(al0, bhv, acc[0][nt], 0, 0, 0);
      acc[1][nt] = __builtin_amdgcn_mfma_f32_16x16x32_bf16(al1, bhv, acc[1][nt], 0, 0, 0);
      acc[0][nt] = __builtin_amdgcn_mfma_f32_16x16x32_bf16(ah0, blv, acc[0][nt], 0, 0, 0);
      acc[1][nt] = __builtin_amdgcn_mfma_f32_16x16x32_bf16(ah1, blv, acc[1][nt], 0, 0, 0);
    }
  }

  const int colg = lane & 15;
  const int rsub = (lane >> 4) * 4;
  #pragma unroll
  for (int nt = 0; nt < NT; ++nt) {
    int c = nt * 16 + colg;
    if (c >= Ncols) continue;
    float bb = bias ? bias[c] : 0.f;
    float scale = 1.f, shift = 0.f;
    if (EPI == EPI_BN || EPI == EPI_BN_RES) {
      scale = g[c] * rsqrtf(va[c] + EPSV);
      shift = be[c] - mu[c] * scale;
    }
    #pragma unroll
    for (int rg = 0; rg < 2; ++rg) {
      #pragma unroll
      for (int i = 0; i < 4; ++i) {
        int r = rowbase + rg * 16 + rsub + i;
        if (r >= NN) continue;
        float v = acc[rg][nt][i] + bb;
        if (EPI == EPI_RELU) {
          v = fmaxf(v, 0.f);
        } else if (EPI == EPI_BN || EPI == EPI_BN_RES) {
          v = fmaxf(v * scale + shift, 0.f);
          if (EPI == EPI_BN_RES) v += res[(long)r * HF + c];
        }
        out[(long)r * ldc + c] = v;
        if (H16 != H16_NONE) {
          float sc = (H16 == H16_SCALED) ? rowscale[r] : 1.f;
          out16[(long)r * HF + c] = __float2half(v * sc);
        }
      }
    }
  }
}

// ---------------- launch ----------------

extern "C" void kernel_launch(void* const* d_in, const int* in_sizes, int n_in,
                              void* d_out, int out_size, void* d_ws, size_t ws_size,
                              hipStream_t stream) {
  const float* features = (const float*)d_in[0];
  const int*   src      = (const int*)d_in[1];
  const int*   dst      = (const int*)d_in[2];
  const float* w_in     = (const float*)d_in[3];
  const float* b_in     = (const float*)d_in[4];
  const float* gc_w     = (const float*)d_in[5];
  const float* gc_b     = (const float*)d_in[6];
  const float* bn_gamma = (const float*)d_in[7];
  const float* bn_beta  = (const float*)d_in[8];
  const float* bn_mean  = (const float*)d_in[9];
  const float* bn_var   = (const float*)d_in[10];
  const float* attn_w1  = (const float*)d_in[11];
  const float* attn_b1  = (const float*)d_in[12];
  const float* attn_w2  = (const float*)d_in[13];
  const float* attn_b2  = (const float*)d_in[14];
  const float* agg_w    = (const float*)d_in[15];
  const float* agg_b    = (const float*)d_in[16];
  const float* out_w    = (const float*)d_in[17];
  const float* out_b    = (const float*)d_in[18];
  float* out = (float*)d_out;

  float* fbase   = (float*)d_ws;
  float* W0 = fbase;                 // h0 -> spmm scratch
  float* W1 = fbase + NH;            // neigh -> a -> h_att -> h(final)
  float* W2 = fbase + 2 * NH;        // agg -> h(L0) -> h(L2)
  float* inv_mean = fbase + 3 * NH;
  float* inv_in   = inv_mean + NN;
  float* inv_out  = inv_in + NN;
  int* indeg   = (int*)(inv_out + NN);
  int* row_ptr = indeg + NN;         // NN+1
  int* bsum    = row_ptr + NN + 1;   // 256
  int* col     = bsum + 256;         // EE
  unsigned* histD  = (unsigned*)(col + EE);   // NX*NN
  unsigned* histS  = histD + (long)NX * NN;   // NX*NN
  unsigned* cursor = histS + (long)NX * NN;   // NX*NN

  // packed bf16 hi/lo weights
  ushort* pk = (ushort*)(cursor + (long)NX * NN);
  const int SZ256 = 8 * 8 * 512;     // K=256, NT=8
  const int SZ128 = 4 * 8 * 512;     // K=128, NT=8
  const int SZOUT = 4 * 4 * 512;     // K=128, NT=4
  ushort* win_hi = pk;  pk += SZ256;  ushort* win_lo = pk;  pk += SZ256;
  ushort* agg_hi = pk;  pk += SZ256;  ushort* agg_lo = pk;  pk += SZ256;
  ushort* at1_hi = pk;  pk += SZ256;  ushort* at1_lo = pk;  pk += SZ256;
  ushort* gch[3], *gcl[3];
  for (int i = 0; i < 3; ++i) { gch[i] = pk; pk += SZ128; gcl[i] = pk; pk += SZ128; }
  ushort* ow_hi = pk;  pk += SZOUT;   ushort* ow_lo = pk;  pk += SZOUT;
  __half* X16 = (__half*)pk;          // NH halfs (fp16 gather rows, reused per stage)

  dim3 b256(256), b128(128);
  const int gN = (NN + 255) / 256;
  const int gE4 = (EE / 4 + 255) / 256;
  const int gblocks = (NN + 127) / 128;
  const int gspmm = (NN + 3) / 4;

  // graph preprocessing (XCD-local atomics)
  hipMemsetAsync(histD, 0, sizeof(unsigned) * 2 * NX * NN, stream);
  count_deg_xcd_kernel<<<gE4, b256, 0, stream>>>((const int4*)src, (const int4*)dst, histS, histD);
  reduce_deg_kernel<<<gN, b256, 0, stream>>>(histD, histS, indeg, inv_mean, inv_in, inv_out);
  scan_block_kernel<<<gN, b256, 0, stream>>>(indeg, row_ptr, bsum, NN);
  scan_block_kernel<<<1, b256, 0, stream>>>(bsum, bsum, nullptr, gN);
  add_offsets_kernel<<<gN, b256, 0, stream>>>(row_ptr, bsum, histD, cursor);
  fill_csr_xcd_kernel<<<gE4, b256, 0, stream>>>((const int4*)src, (const int4*)dst, cursor, col);

  // weight prepack
  prepack_kernel<<<(SZ256 + 255) / 256, b256, 0, stream>>>(w_in,    HF, HF, 8, win_hi, win_lo, SZ256);
  prepack_kernel<<<(SZ256 + 255) / 256, b256, 0, stream>>>(agg_w,   HF, HF, 8, agg_hi, agg_lo, SZ256);
  prepack_kernel<<<(SZ256 + 255) / 256, b256, 0, stream>>>(attn_w1, HF, HF, 8, at1_hi, at1_lo, SZ256);
  for (int i = 0; i < 3; ++i)
    prepack_kernel<<<(SZ128 + 255) / 256, b256, 0, stream>>>(gc_w + (long)i * HF * HF, HF, HF, 8, gch[i], gcl[i], SZ128);
  prepack_kernel<<<(SZOUT + 255) / 256, b256, 0, stream>>>(out_w, CC, CC, 4, ow_hi, ow_lo, SZOUT);

  // h0 = relu(features @ w_in + b_in)            -> W0 (+fp16 raw -> X16)
  mgemm_kernel<8, 8, EPI_RELU, H16_RAW><<<gblocks, b256, 0, stream>>>(
      features, INF_, features + 128, INF_, win_hi, win_lo, b_in,
      nullptr, nullptr, nullptr, nullptr, nullptr, W0, HF, HF, X16, nullptr);
  // neigh = mean-agg(h0)                          -> W1
  spmm16_kernel<<<gspmm, b256, 0, stream>>>(row_ptr, col, (const __half2*)X16, inv_mean, W1);
  // agg = relu([h0|neigh] @ agg_w + agg_b)        -> W2
  mgemm_kernel<8, 8, EPI_RELU, H16_NONE><<<gblocks, b256, 0, stream>>>(
      W0, HF, W1, HF, agg_hi, agg_lo, agg_b,
      nullptr, nullptr, nullptr, nullptr, nullptr, W2, HF, HF, nullptr, nullptr);
  // a = relu([h0|agg] @ attn_w1 + attn_b1)        -> W1
  mgemm_kernel<8, 8, EPI_RELU, H16_NONE><<<gblocks, b256, 0, stream>>>(
      W0, HF, W2, HF, at1_hi, at1_lo, attn_b1,
      nullptr, nullptr, nullptr, nullptr, nullptr, W1, HF, HF, nullptr, nullptr);
  // h_att = h0 + agg * sigmoid(a@w2+b2)           -> W1 (+fp16 *inv_out -> X16)
  attn_hatt_kernel<<<NN, b128, 0, stream>>>(W1, attn_w2, attn_b2, W0, W2, inv_out, W1, X16);

  // layer 0: spmm(X16)->W0 ; relu(BN(W0@gc0+b0))          -> W2 (+fp16 -> X16)
  spmm16_kernel<<<gspmm, b256, 0, stream>>>(row_ptr, col, (const __half2*)X16, inv_in, W0);
  mgemm_kernel<4, 8, EPI_BN, H16_SCALED><<<gblocks, b256, 0, stream>>>(
      W0, HF, nullptr, 0, gch[0], gcl[0], gc_b,
      bn_gamma, bn_beta, bn_mean, bn_var, nullptr, W2, HF, HF, X16, inv_out);
  // layer 1: spmm(X16)->W0 ; relu(BN(W0@gc1+b1)) + W2     -> W1 (+fp16 -> X16)
  spmm16_kernel<<<gspmm, b256, 0, stream>>>(row_ptr, col, (const __half2*)X16, inv_in, W0);
  mgemm_kernel<4, 8, EPI_BN_RES, H16_SCALED><<<gblocks, b256, 0, stream>>>(
      W0, HF, nullptr, 0, gch[1], gcl[1], gc_b + HF,
      bn_gamma + HF, bn_beta + HF, bn_mean + HF, bn_var + HF, W2, W1, HF, HF, X16, inv_out);
  // layer 2: spmm(X16)->W0 ; relu(BN(W0@gc2+b2)) + W1     -> W2
  spmm16_kernel<<<gspmm, b256, 0, stream>>>(row_ptr, col, (const __half2*)X16, inv_in, W0);
  mgemm_kernel<4, 8, EPI_BN_RES, H16_NONE><<<gblocks, b256, 0, stream>>>(
      W0, HF, nullptr, 0, gch[2], gcl[2], gc_b + 2 * HF,
      bn_gamma + 2 * HF, bn_beta + 2 * HF, bn_mean + 2 * HF, bn_var + 2 * HF, W1, W2, HF, HF,
      nullptr, nullptr);

  // out = W2 @ out_w + out_b                      -> d_out
  mgemm_kernel<4, 4, EPI_NONE, H16_NONE><<<gblocks, b256, 0, stream>>>(
      W2, HF, nullptr, 0, ow_hi, ow_lo, out_b,
      nullptr, nullptr, nullptr, nullptr, nullptr, out, CC, CC, nullptr, nullptr);
}